// Round 3
// baseline (169.393 us; speedup 1.0000x reference)
//
#include <hip/hip_runtime.h>

#define N_ROWS 8192
#define D_IN   4096
#define D_F    8192

// Radix-4 Hadamard butterfly over two index bits.
__device__ __forceinline__ void h4(float& a, float& b, float& c, float& d) {
  float t0 = a + b, t1 = a - b, t2 = c + d, t3 = c - d;
  a = t0 + t2; c = t0 - t2;
  b = t1 + t3; d = t1 - t3;
}

// One block = one row (4096 elements, 12 index bits).
//   Phase 1 (regs): bits {0,1} (inside float4) x {10,11} (chunk)
//   Phase 2 (LDS RMW): bits {2,3,4,5} in-thread, register H16
//   Phase 3 (LDS RMW): bits {6,7,8,9} in-thread, register H16
// LDS swizzle a(e) = e ^ ((e>>4)&0x1C): every access pattern conflict-free.
// Phase 3 writes back to the SAME swizzled addresses it read -> z stays in
// swizzled layout; the gather swizzles its indices instead (2 VALU/elem).
// Double-buffered zbuf: degree d+1's staging write overlaps degree d's
// gather (different buffer) -> 3 barriers/degree, 9 total.
__global__ __launch_bounds__(256, 5) void srht_kernel(
    const float* __restrict__ x,
    const float* __restrict__ rad,
    const int* __restrict__ perm,
    float* __restrict__ out)
{
  __shared__ __align__(16) float zbuf[2][D_IN];   // 32 KiB double buffer
  const int t   = threadIdx.x;
  const int row = blockIdx.x;

  // Load x row once (coalesced float4): elem e = c*1024 + t*4 + i
  float xr[4][4];
  const float4* xrow = reinterpret_cast<const float4*>(x) + (size_t)row * (D_IN / 4);
  #pragma unroll
  for (int c = 0; c < 4; ++c) {
    float4 tv = xrow[c * 256 + t];
    xr[c][0] = tv.x; xr[c][1] = tv.y; xr[c][2] = tv.z; xr[c][3] = tv.w;
  }

  const float INV = 0.01104854345603981f;  // 1/sqrt(8192)
  float acc[32];
  #pragma unroll
  for (int k = 0; k < 32; ++k) acc[k] = INV;

  // phase-2 base: e2 bits: [1:0]=t[1:0], [7:6]=t[3:2], [9:8]=t[5:4], [11:10]=t[7:6]
  const int e2  = (t & 3) | ((t & 0xFC) << 4);
  const int p2b = e2 ^ ((e2 >> 4) & 0x1C);     // thread-constant swizzled base
  // phase-3 base: e3 bits: [5:0]=t[5:0], [11:10]=t[7:6]
  const int e3  = (t & 0x3F) | ((t & 0xC0) << 4);

  // rad-multiply + register H4s over bits {0,1} and {10,11}
  auto compute_v = [&](int d, float v[4][4]) {
    const float4* rrow = reinterpret_cast<const float4*>(rad) + d * (D_IN / 4);
    #pragma unroll
    for (int c = 0; c < 4; ++c) {
      float4 rv = rrow[c * 256 + t];
      v[c][0] = xr[c][0] * rv.x;
      v[c][1] = xr[c][1] * rv.y;
      v[c][2] = xr[c][2] * rv.z;
      v[c][3] = xr[c][3] * rv.w;
    }
    #pragma unroll
    for (int c = 0; c < 4; ++c) h4(v[c][0], v[c][1], v[c][2], v[c][3]);
    #pragma unroll
    for (int i = 0; i < 4; ++i) h4(v[0][i], v[1][i], v[2][i], v[3][i]);
  };
  // swizzled float4 staging write (conflict-free)
  auto write_v = [&](float* buf, float v[4][4]) {
    #pragma unroll
    for (int c = 0; c < 4; ++c) {
      int e = c * 1024 + t * 4;
      int a = e ^ ((e >> 4) & 0x1C);
      *reinterpret_cast<float4*>(&buf[a]) =
          make_float4(v[c][0], v[c][1], v[c][2], v[c][3]);
    }
  };

  {
    float v[4][4];
    compute_v(0, v);
    write_v(zbuf[0], v);
  }

  #pragma unroll
  for (int d = 0; d < 3; ++d) {
    float* cur = zbuf[d & 1];
    __syncthreads();   // staging write (prev tail / preamble) visible

    // ---- phase 2: bits {2,3,4,5}; same-address RMW
    float w[16];
    #pragma unroll
    for (int j = 0; j < 16; ++j) w[j] = cur[p2b ^ (j << 2)];
    #pragma unroll
    for (int a = 0; a < 4; ++a) h4(w[4*a], w[4*a+1], w[4*a+2], w[4*a+3]);
    #pragma unroll
    for (int b = 0; b < 4; ++b) h4(w[b], w[b+4], w[b+8], w[b+12]);
    #pragma unroll
    for (int j = 0; j < 16; ++j) cur[p2b ^ (j << 2)] = w[j];
    __syncthreads();

    // ---- phase 3: bits {6,7,8,9}; same-address RMW (z stays swizzled)
    #pragma unroll
    for (int j = 0; j < 16; ++j)
      w[j] = cur[e3 ^ ((j << 6) | ((j & 7) << 2))];
    #pragma unroll
    for (int a = 0; a < 4; ++a) h4(w[4*a], w[4*a+1], w[4*a+2], w[4*a+3]);
    #pragma unroll
    for (int b = 0; b < 4; ++b) h4(w[b], w[b+4], w[b+8], w[b+12]);
    #pragma unroll
    for (int j = 0; j < 16; ++j)
      cur[e3 ^ ((j << 6) | ((j & 7) << 2))] = w[j];
    __syncthreads();

    // ---- tail (barrier-free): stage next degree into other buffer + gather
    if (d < 2) {
      float v[4][4];
      compute_v(d + 1, v);
      write_v(zbuf[(d + 1) & 1], v);
    }
    const int4* p4 = reinterpret_cast<const int4*>(perm) + d * (D_F / 4);
    #pragma unroll
    for (int it = 0; it < 8; ++it) {
      int4 p = p4[it * 256 + t];
      int a0 = p.x ^ ((p.x >> 4) & 0x1C);
      int a1 = p.y ^ ((p.y >> 4) & 0x1C);
      int a2 = p.z ^ ((p.z >> 4) & 0x1C);
      int a3 = p.w ^ ((p.w >> 4) & 0x1C);
      acc[it*4+0] *= cur[a0];
      acc[it*4+1] *= cur[a1];
      acc[it*4+2] *= cur[a2];
      acc[it*4+3] *= cur[a3];
    }
  }

  // ---- coalesced float4 output
  float4* o4 = reinterpret_cast<float4*>(out + (size_t)row * D_F);
  #pragma unroll
  for (int it = 0; it < 8; ++it)
    o4[it * 256 + t] =
        make_float4(acc[it*4+0], acc[it*4+1], acc[it*4+2], acc[it*4+3]);
}

extern "C" void kernel_launch(void* const* d_in, const int* in_sizes, int n_in,
                              void* d_out, int out_size, void* d_ws, size_t ws_size,
                              hipStream_t stream) {
  const float* x   = (const float*)d_in[0];
  const float* rad = (const float*)d_in[1];
  const int* perm  = (const int*)d_in[2];
  float* out       = (float*)d_out;
  srht_kernel<<<N_ROWS, 256, 0, stream>>>(x, rad, perm, out);
}

// Round 4
// 120.038 us; speedup vs baseline: 1.4112x; 1.4112x over previous
//
#include <hip/hip_runtime.h>

#define N_ROWS 8192
#define D_IN   4096
#define D_F    8192

// Radix-4 Hadamard butterfly over two index bits.
__device__ __forceinline__ void h4(float& a, float& b, float& c, float& d) {
  float t0 = a + b, t1 = a - b, t2 = c + d, t3 = c - d;
  a = t0 + t2; c = t0 - t2;
  b = t1 + t3; d = t1 - t3;
}

// DPP move: result lane gets source lane per CTRL (quad_perm / row ops).
template<int CTRL>
__device__ __forceinline__ float dppf(float v) {
  int iv = __builtin_bit_cast(int, v);
  int r = __builtin_amdgcn_update_dpp(0, iv, CTRL, 0xF, 0xF, true);
  return __builtin_bit_cast(float, r);
}

#define DPP_QUAD_XOR1       0xB1   // quad_perm(1,0,3,2)
#define DPP_QUAD_XOR2       0x4E   // quad_perm(2,3,0,1)
#define DPP_QUAD_XOR3       0x1B   // quad_perm(3,2,1,0)
#define DPP_ROW_HALF_MIRROR 0x141  // XOR 7 within 16-lane row
#define DPP_ROW_ROR8        0x128  // rotate 8 within row == XOR 8

// One block = one row (4096 elements, 12 index bits).
// elem e = c*1024 + t*4 + i:  i=e[1:0], lane=e[7:2], wv=e[9:8], c=e[11:10]
//  - bits {0,1},{10,11}: register h4 (from global load)
//  - bits {2..7} (lane bits): VALU cross-lane — DPP quad_perm XOR1/XOR2,
//    2-DPP XOR4, row_ror:8 (XOR8), permlane16/32_swap (XOR16/32).
//    Butterfly: v = fma(sgn, v, partner), sgn=+1 lower/-1 upper (hoisted).
//  - bits {8,9} (cross-wave): single b128 LDS RMW trip, conflict-free.
// z ends in NATURAL layout -> gather needs no index swizzle.
// LDS traffic/degree: 16KB stage write + 32KB b128 trip + 32KB gather.
__global__ __launch_bounds__(256, 4) void srht_kernel(
    const float* __restrict__ x,
    const float* __restrict__ rad,
    const int* __restrict__ perm,
    float* __restrict__ out)
{
  __shared__ __align__(16) float zbuf[D_IN];   // 16 KiB
  const int t    = threadIdx.x;
  const int lane = t & 63;
  const int wv   = t >> 6;
  const int row  = blockIdx.x;

  // per-stage butterfly signs for the 6 lane bits
  const float sg0 = (lane & 1)  ? -1.f : 1.f;
  const float sg1 = (lane & 2)  ? -1.f : 1.f;
  const float sg2 = (lane & 4)  ? -1.f : 1.f;
  const float sg3 = (lane & 8)  ? -1.f : 1.f;
  const float sg4 = (lane & 16) ? -1.f : 1.f;
  const float sg5 = (lane & 32) ? -1.f : 1.f;

  // Load x row once (coalesced float4): elem e = c*1024 + t*4 + i
  float xr[4][4];
  const float4* xrow = reinterpret_cast<const float4*>(x) + (size_t)row * (D_IN / 4);
  #pragma unroll
  for (int c = 0; c < 4; ++c) {
    float4 tv = xrow[c * 256 + t];
    xr[c][0] = tv.x; xr[c][1] = tv.y; xr[c][2] = tv.z; xr[c][3] = tv.w;
  }

  const float INV = 0.01104854345603981f;  // 1/sqrt(8192)
  float acc[32];
  #pragma unroll
  for (int k = 0; k < 32; ++k) acc[k] = INV;

  float4* z4 = reinterpret_cast<float4*>(zbuf);

  #pragma unroll 1
  for (int d = 0; d < 3; ++d) {
    // ---- rad multiply + register h4 over bits {0,1} and {10,11}
    float v[4][4];
    const float4* rrow = reinterpret_cast<const float4*>(rad) + d * (D_IN / 4);
    #pragma unroll
    for (int c = 0; c < 4; ++c) {
      float4 rv = rrow[c * 256 + t];
      v[c][0] = xr[c][0] * rv.x;
      v[c][1] = xr[c][1] * rv.y;
      v[c][2] = xr[c][2] * rv.z;
      v[c][3] = xr[c][3] * rv.w;
    }
    #pragma unroll
    for (int c = 0; c < 4; ++c) h4(v[c][0], v[c][1], v[c][2], v[c][3]);
    #pragma unroll
    for (int i = 0; i < 4; ++i) h4(v[0][i], v[1][i], v[2][i], v[3][i]);

    // ---- lane-bit stages (pure VALU cross-lane)
    #pragma unroll
    for (int c = 0; c < 4; ++c)
      #pragma unroll
      for (int i = 0; i < 4; ++i) {     // XOR 1 (e-bit 2)
        float p = dppf<DPP_QUAD_XOR1>(v[c][i]);
        v[c][i] = fmaf(sg0, v[c][i], p);
      }
    #pragma unroll
    for (int c = 0; c < 4; ++c)
      #pragma unroll
      for (int i = 0; i < 4; ++i) {     // XOR 2 (e-bit 3)
        float p = dppf<DPP_QUAD_XOR2>(v[c][i]);
        v[c][i] = fmaf(sg1, v[c][i], p);
      }
    #pragma unroll
    for (int c = 0; c < 4; ++c)
      #pragma unroll
      for (int i = 0; i < 4; ++i) {     // XOR 4 (e-bit 4): XOR7 then XOR3
        float p = dppf<DPP_QUAD_XOR3>(dppf<DPP_ROW_HALF_MIRROR>(v[c][i]));
        v[c][i] = fmaf(sg2, v[c][i], p);
      }
    #pragma unroll
    for (int c = 0; c < 4; ++c)
      #pragma unroll
      for (int i = 0; i < 4; ++i) {     // XOR 8 (e-bit 5)
        float p = dppf<DPP_ROW_ROR8>(v[c][i]);
        v[c][i] = fmaf(sg3, v[c][i], p);
      }
    #pragma unroll
    for (int c = 0; c < 4; ++c)
      #pragma unroll
      for (int i = 0; i < 4; ++i) {     // XOR 16 (e-bit 6)
#if __has_builtin(__builtin_amdgcn_permlane16_swap)
        unsigned iv = __builtin_bit_cast(unsigned, v[c][i]);
        auto r = __builtin_amdgcn_permlane16_swap(iv, iv, false, false);
        float p = __builtin_bit_cast(float, (lane & 16) ? r[0] : r[1]);
#else
        float p = __shfl_xor(v[c][i], 16, 64);
#endif
        v[c][i] = fmaf(sg4, v[c][i], p);
      }
    #pragma unroll
    for (int c = 0; c < 4; ++c)
      #pragma unroll
      for (int i = 0; i < 4; ++i) {     // XOR 32 (e-bit 7)
#if __has_builtin(__builtin_amdgcn_permlane32_swap)
        unsigned iv = __builtin_bit_cast(unsigned, v[c][i]);
        auto r = __builtin_amdgcn_permlane32_swap(iv, iv, false, false);
        float p = __builtin_bit_cast(float, (lane & 32) ? r[0] : r[1]);
#else
        float p = __shfl_xor(v[c][i], 32, 64);
#endif
        v[c][i] = fmaf(sg5, v[c][i], p);
      }

    __syncthreads();   // previous degree's gather must be done with zbuf
    // ---- stage write (natural layout, consecutive float4s: conflict-free)
    #pragma unroll
    for (int c = 0; c < 4; ++c)
      z4[c * 256 + t] = make_float4(v[c][0], v[c][1], v[c][2], v[c][3]);
    __syncthreads();

    // ---- cross-wave trip: bits {8,9}. Thread RMWs its own 4 float4s
    //      (disjoint sets, no barrier between read and write).
    float q[4][4];
    #pragma unroll
    for (int ww = 0; ww < 4; ++ww) {
      float4 tv = z4[wv * 256 + ww * 64 + lane];
      q[ww][0] = tv.x; q[ww][1] = tv.y; q[ww][2] = tv.z; q[ww][3] = tv.w;
    }
    #pragma unroll
    for (int i = 0; i < 4; ++i) h4(q[0][i], q[1][i], q[2][i], q[3][i]);
    #pragma unroll
    for (int ww = 0; ww < 4; ++ww)
      z4[wv * 256 + ww * 64 + lane] =
          make_float4(q[ww][0], q[ww][1], q[ww][2], q[ww][3]);
    __syncthreads();

    // ---- gather this degree into the running product (natural indices)
    const int4* p4 = reinterpret_cast<const int4*>(perm) + d * (D_F / 4);
    #pragma unroll
    for (int it = 0; it < 8; ++it) {
      int4 p = p4[it * 256 + t];
      acc[it*4+0] *= zbuf[p.x];
      acc[it*4+1] *= zbuf[p.y];
      acc[it*4+2] *= zbuf[p.z];
      acc[it*4+3] *= zbuf[p.w];
    }
  }

  // ---- coalesced float4 output
  float4* o4 = reinterpret_cast<float4*>(out + (size_t)row * D_F);
  #pragma unroll
  for (int it = 0; it < 8; ++it)
    o4[it * 256 + t] =
        make_float4(acc[it*4+0], acc[it*4+1], acc[it*4+2], acc[it*4+3]);
}

extern "C" void kernel_launch(void* const* d_in, const int* in_sizes, int n_in,
                              void* d_out, int out_size, void* d_ws, size_t ws_size,
                              hipStream_t stream) {
  const float* x   = (const float*)d_in[0];
  const float* rad = (const float*)d_in[1];
  const int* perm  = (const int*)d_in[2];
  float* out       = (float*)d_out;
  srht_kernel<<<N_ROWS, 256, 0, stream>>>(x, rad, perm, out);
}